// Round 7
// baseline (1292.613 us; speedup 1.0000x reference)
//
#include <hip/hip_runtime.h>

typedef unsigned short ushort_t;
typedef _Float16 f16x8 __attribute__((ext_vector_type(8)));
typedef float f32x4 __attribute__((ext_vector_type(4)));
typedef unsigned short us8 __attribute__((ext_vector_type(8)));

#define H_DIM 256
#define OUT_DIM 256

__device__ inline float lrelu(float v) { return v > 0.f ? v : 0.01f * v; }

__device__ inline unsigned short f2h(float f) {
    _Float16 h = (_Float16)f;
    unsigned short u;
    __builtin_memcpy(&u, &h, 2);
    return u;
}

__device__ inline float h2f(unsigned short u) {
    _Float16 h;
    __builtin_memcpy(&h, &u, 2);
    return (float)h;
}

// ---------- prep kernels ----------

__global__ void k_gather_x0(const float* __restrict__ sst, const int* __restrict__ mask,
                            float* __restrict__ x0, int NT, int Nn, int F) {
    int v = blockIdx.x * 256 + threadIdx.x;
    if (v < NT) {
        int b = v / Nn;
        int i = v - b * Nn;
        x0[v] = sst[(size_t)b * F + mask[i]];
    }
}

__global__ void k_count(const int* __restrict__ dst, int* __restrict__ cnt, int E) {
    int e = blockIdx.x * 256 + threadIdx.x;
    if (e < E) atomicAdd(&cnt[dst[e]], 1);
}

__global__ void k_dis(const int* __restrict__ cnt, float* __restrict__ dis, int NT) {
    int v = blockIdx.x * 256 + threadIdx.x;
    if (v < NT) dis[v] = rsqrtf((float)cnt[v] + 1.0f);
}

__global__ void k_scan_block(const int* __restrict__ cnt, int* __restrict__ bsum, int NT) {
    __shared__ int s[256];
    int i = blockIdx.x * 256 + threadIdx.x;
    s[threadIdx.x] = (i < NT) ? cnt[i] : 0;
    __syncthreads();
    for (int o = 128; o > 0; o >>= 1) {
        if (threadIdx.x < o) s[threadIdx.x] += s[threadIdx.x + o];
        __syncthreads();
    }
    if (threadIdx.x == 0) bsum[blockIdx.x] = s[0];
}

__global__ void k_scan_top(const int* __restrict__ bsum, int* __restrict__ bpre, int nb) {
    __shared__ int s[512];
    int t = threadIdx.x;
    int v = (t < nb) ? bsum[t] : 0;
    s[t] = v;
    __syncthreads();
    for (int o = 1; o < nb; o <<= 1) {
        int add = (t >= o) ? s[t - o] : 0;
        __syncthreads();
        s[t] += add;
        __syncthreads();
    }
    if (t < nb) bpre[t] = s[t] - v;   // exclusive
}

__global__ void k_scan_scatter(const int* __restrict__ cnt, const int* __restrict__ bpre,
                               int* __restrict__ startp, int* __restrict__ cursor, int NT) {
    __shared__ int s[256];
    int t = threadIdx.x;
    int i = blockIdx.x * 256 + t;
    int v = (i < NT) ? cnt[i] : 0;
    s[t] = v;
    __syncthreads();
    for (int o = 1; o < 256; o <<= 1) {
        int add = (t >= o) ? s[t - o] : 0;
        __syncthreads();
        s[t] += add;
        __syncthreads();
    }
    int excl = s[t] - v + bpre[blockIdx.x];
    if (i < NT) { startp[i] = excl; cursor[i] = excl; }
}

__global__ void k_fill(const int* __restrict__ src, const int* __restrict__ dst,
                       const float* __restrict__ dis, int* __restrict__ cursor,
                       int* __restrict__ csrc, float* __restrict__ cnorm, int E) {
    int e = blockIdx.x * 256 + threadIdx.x;
    if (e < E) {
        int s = src[e], d = dst[e];
        int p = atomicAdd(&cursor[d], 1);
        csrc[p] = s;
        cnorm[p] = dis[s] * dis[d];
    }
}

__global__ void k_prepW(const float* __restrict__ Ws, ushort_t* __restrict__ Wt, int total) {
    int idx = blockIdx.x * 256 + threadIdx.x;
    if (idx < total) {
        int l = idx >> 16;          // layer
        int rem = idx & 65535;
        int k = rem >> 8;           // input dim
        int n = rem & 255;          // output dim
        Wt[(l << 16) + (n << 8) + k] = f2h(Ws[idx]);
    }
}

// ---------- layer 1 (scalar input) ----------

__global__ void k_agg0(const float* __restrict__ x0, const int* __restrict__ startp,
                       const int* __restrict__ cnt, const int* __restrict__ csrc,
                       const float* __restrict__ cnorm, const float* __restrict__ dis,
                       float* __restrict__ y0, int NT) {
    int v = blockIdx.x * 256 + threadIdx.x;
    if (v >= NT) return;
    float d = dis[v];
    float acc = d * d * x0[v];
    int s = startp[v], e = s + cnt[v];
    for (int i = s; i < e; i++) acc += cnorm[i] * x0[csrc[i]];
    y0[v] = acc;
}

__global__ void k_expand(const float* __restrict__ x0, const float* __restrict__ y0,
                         const float* __restrict__ W1, const float* __restrict__ b1,
                         ushort_t* __restrict__ xh, int NT) {
    int idx = blockIdx.x * 256 + threadIdx.x;      // one float4-worth each, NT*64 total
    int v = idx >> 6;
    int q = idx & 63;
    if (v >= NT) return;
    float xv = x0[v], yv = y0[v];
    float4 w = ((const float4*)W1)[q];
    float4 b = ((const float4*)b1)[q];
    ushort4 o;
    o.x = f2h(xv + lrelu(yv * w.x + b.x));
    o.y = f2h(xv + lrelu(yv * w.y + b.y));
    o.z = f2h(xv + lrelu(yv * w.z + b.z));
    o.w = f2h(xv + lrelu(yv * w.w + b.w));
    ((ushort4*)xh)[(size_t)v * 64 + q] = o;
}

// ---------- GEMM: z = xh @ W (fp16 MFMA, f32 accumulate, fp16 out) ----------
// xh: [NT][256] fp16, Wt: [n][k] fp16, z: [NT][256] fp16.
// Block: 512 thr = 8 waves (2 M x 4 N), tile BM=128 BN=256 BK=64.

__global__ __launch_bounds__(512, 4) void k_gemm(const ushort_t* __restrict__ xh,
                                                 const ushort_t* __restrict__ Wt,
                                                 ushort_t* __restrict__ z) {
    __shared__ ushort_t As[128][72];
    __shared__ ushort_t Bs[256][72];
    int tid = threadIdx.x;
    int wave = tid >> 6, lane = tid & 63;
    int wm = wave >> 2, wn = wave & 3;           // 2 x 4 wave grid, each 64x64
    size_t rowbase = (size_t)blockIdx.x * 128;

    f32x4 acc[4][4];
    for (int mi = 0; mi < 4; mi++)
        for (int ni = 0; ni < 4; ni++)
            acc[mi][ni] = (f32x4){0.f, 0.f, 0.f, 0.f};

    for (int kk = 0; kk < H_DIM; kk += 64) {
        // stage A: 128 rows x 64 fp16 (16 KB) -> 1024 16B chunks, 2 passes
        for (int p = 0; p < 2; p++) {
            int idx = p * 512 + tid;
            int r = idx >> 3, c8 = idx & 7;
            *(uint4*)&As[r][c8 * 8] = *(const uint4*)(xh + (rowbase + r) * H_DIM + kk + c8 * 8);
        }
        // stage B: 256 rows x 64 fp16 (32 KB) -> 2048 16B chunks, 4 passes
        for (int p = 0; p < 4; p++) {
            int idx = p * 512 + tid;
            int r = idx >> 3, c8 = idx & 7;
            *(uint4*)&Bs[r][c8 * 8] = *(const uint4*)(Wt + (size_t)r * H_DIM + kk + c8 * 8);
        }
        __syncthreads();
        int rl = lane & 15;
        for (int kc = 0; kc < 2; kc++) {
            int kb = kc * 32 + ((lane >> 4) << 3);
            f16x8 af[4], bfr[4];
            for (int mi = 0; mi < 4; mi++)
                af[mi] = *(const f16x8*)&As[wm * 64 + mi * 16 + rl][kb];
            for (int ni = 0; ni < 4; ni++)
                bfr[ni] = *(const f16x8*)&Bs[wn * 64 + ni * 16 + rl][kb];
            for (int mi = 0; mi < 4; mi++)
                for (int ni = 0; ni < 4; ni++)
                    acc[mi][ni] = __builtin_amdgcn_mfma_f32_16x16x32_f16(
                        af[mi], bfr[ni], acc[mi][ni], 0, 0, 0);
        }
        __syncthreads();
    }

    // epilogue: C frag layout col=lane&15, row=(lane>>4)*4+reg; z = fp16(acc)
    int rl = lane & 15, rh = lane >> 4;
    for (int ni = 0; ni < 4; ni++) {
        int col = wn * 64 + ni * 16 + rl;
        for (int mi = 0; mi < 4; mi++) {
            size_t row = rowbase + wm * 64 + mi * 16 + rh * 4;
            for (int r = 0; r < 4; r++)
                z[(row + r) * H_DIM + col] = f2h(acc[mi][ni][r]);
        }
    }
}

// ---------- aggregate + bias + leaky + residual (in-place fp16 xh update) ----------
// 2 nodes per wave: half-wave (32 lanes x 16B) covers one 512B fp16 row.
// Unroll-8 predicated gather: up to 8 row loads (4KB/wave) in flight.

__global__ void k_aggres(const ushort_t* __restrict__ z, const int* __restrict__ startp,
                         const int* __restrict__ cnt, const int* __restrict__ csrc,
                         const float* __restrict__ cnorm, const float* __restrict__ dis,
                         const float* __restrict__ bias, ushort_t* __restrict__ xh, int NT) {
    int tid = threadIdx.x;
    int wave = tid >> 6, lane = tid & 63;
    int h = lane >> 5, hl = lane & 31;
    int v = blockIdx.x * 8 + wave * 2 + h;
    if (v >= NT) return;

    // hoisted independent loads (in flight during gather)
    float d = dis[v];
    int s = startp[v], cv = cnt[v];
    us8 a  = *(const us8*)(z  + (size_t)v * H_DIM + hl * 8);
    us8 xr = *(const us8*)(xh + (size_t)v * H_DIM + hl * 8);
    float4 bv0 = *(const float4*)(bias + hl * 8);
    float4 bv1 = *(const float4*)(bias + hl * 8 + 4);

    float sn = d * d;
    float acc[8];
    #pragma unroll
    for (int c = 0; c < 8; c++) acc[c] = sn * h2f(a[c]);

    for (int i = 0; i < cv; i += 8) {
        int   idx[8];
        float w[8];
        #pragma unroll
        for (int k = 0; k < 8; k++) {
            int t = i + k;
            int j = s + ((t < cv) ? t : (cv - 1));   // clamp: wasted loads hit hot line
            idx[k] = csrc[j];
            w[k]   = (t < cv) ? cnorm[j] : 0.f;
        }
        us8 r[8];
        #pragma unroll
        for (int k = 0; k < 8; k++)
            r[k] = *(const us8*)(z + (size_t)idx[k] * H_DIM + hl * 8);
        #pragma unroll
        for (int k = 0; k < 8; k++) {
            #pragma unroll
            for (int c = 0; c < 8; c++)
                acc[c] += w[k] * h2f(r[k][c]);
        }
    }

    us8 o;
    #pragma unroll
    for (int c = 0; c < 4; c++) {
        o[c]     = f2h(h2f(xr[c])     + lrelu(acc[c]     + ((const float*)&bv0)[c]));
        o[c + 4] = f2h(h2f(xr[c + 4]) + lrelu(acc[c + 4] + ((const float*)&bv1)[c]));
    }
    *(us8*)(xh + (size_t)v * H_DIM + hl * 8) = o;
}

// ---------- pooling (3-stage tree) + head ----------

__global__ void k_pool1(const ushort_t* __restrict__ xh, float* __restrict__ partial) {
    // 64 nodes per block, 256 threads = 4 waves; wave w handles nodes i*4+w,
    // lane owns channels [lane*4, lane*4+4)
    __shared__ float s[4][256];
    int t = threadIdx.x;
    int w = t >> 6, lane = t & 63;
    size_t nodebase = (size_t)blockIdx.x * 64;
    float4 acc = make_float4(0.f, 0.f, 0.f, 0.f);
    for (int i = 0; i < 16; i++) {
        size_t node = nodebase + i * 4 + w;
        ushort4 v = *(const ushort4*)(xh + node * H_DIM + lane * 4);
        acc.x += h2f(v.x); acc.y += h2f(v.y); acc.z += h2f(v.z); acc.w += h2f(v.w);
    }
    *(float4*)&s[w][lane * 4] = acc;
    __syncthreads();
    float sum = s[0][t] + s[1][t] + s[2][t] + s[3][t];
    partial[(size_t)blockIdx.x * H_DIM + t] = sum;
}

__global__ void k_pool2(const float* __restrict__ partial, float* __restrict__ partial2,
                        int rowsPerChunk) {
    // grid = B * chunksPerBatch; block 256
    int blk = blockIdx.x, t = threadIdx.x;
    size_t rowbase = (size_t)blk * rowsPerChunk;
    float s = 0.f;
    for (int j = 0; j < rowsPerChunk; j++)
        s += partial[(rowbase + j) * H_DIM + t];
    partial2[(size_t)blk * H_DIM + t] = s;
}

__global__ void k_pool3(const float* __restrict__ partial2, float* __restrict__ pooled,
                        int chunksPerBatch, float inv) {
    int b = blockIdx.x, t = threadIdx.x;
    float s = 0.f;
    for (int j = 0; j < chunksPerBatch; j++)
        s += partial2[((size_t)b * chunksPerBatch + j) * H_DIM + t];
    pooled[b * H_DIM + t] = s * inv;
}

__global__ void k_head(const float* __restrict__ pooled, const float* __restrict__ Wh,
                       const float* __restrict__ bh, float* __restrict__ out) {
    int b = blockIdx.x, o = threadIdx.x;
    float acc = bh[o];
    for (int h = 0; h < H_DIM; h++) acc += pooled[b * H_DIM + h] * Wh[h * OUT_DIM + o];
    out[b * OUT_DIM + o] = acc;
}

// ---------- host ----------

extern "C" void kernel_launch(void* const* d_in, const int* in_sizes, int n_in,
                              void* d_out, int out_size, void* d_ws, size_t ws_size,
                              hipStream_t stream) {
    const float* sst  = (const float*)d_in[0];
    const int*   mask = (const int*)d_in[1];
    const int*   eidx = (const int*)d_in[2];
    const float* W1   = (const float*)d_in[3];
    const float* b1   = (const float*)d_in[4];
    const float* Ws   = (const float*)d_in[5];
    const float* bs   = (const float*)d_in[6];
    const float* Wh   = (const float*)d_in[7];
    const float* bh   = (const float*)d_in[8];

    const int B  = out_size / OUT_DIM;               // 2
    const int Nn = in_sizes[1];                      // 65536
    const int E  = in_sizes[2] / 2;                  // 1048576
    const int F  = in_sizes[0] / B;                  // 686364
    const int DEPTH = in_sizes[5] / (H_DIM * H_DIM); // 8
    const int NT = B * Nn;                           // 131072

    // workspace carve-up (256B aligned) — total ~160 MB
    size_t off = 0;
    char* base = (char*)d_ws;
    auto alloc = [&](size_t bytes) -> void* {
        void* p = base + off;
        off += (bytes + 255) & ~(size_t)255;
        return p;
    };
    ushort_t* xh      = (ushort_t*)alloc((size_t)NT * H_DIM * 2);  // 67.1 MB (fp16 residual)
    ushort_t* zbuf    = (ushort_t*)alloc((size_t)NT * H_DIM * 2);  // 67.1 MB (fp16)
    float*    x0      = (float*)alloc((size_t)NT * 4);
    float*    y0      = (float*)alloc((size_t)NT * 4);
    int*      cnt     = (int*)alloc((size_t)NT * 4);
    int*      startp  = (int*)alloc((size_t)NT * 4);
    int*      cursor  = (int*)alloc((size_t)NT * 4);
    float*    dis     = (float*)alloc((size_t)NT * 4);
    int*      bsum    = (int*)alloc(4096);
    int*      bpre    = (int*)alloc(4096);
    int*      csrc    = (int*)alloc((size_t)E * 4);
    float*    cnorm   = (float*)alloc((size_t)E * 4);
    ushort_t* Wt      = (ushort_t*)alloc((size_t)DEPTH * H_DIM * H_DIM * 2);  // fp16
    float*    partial = (float*)alloc((size_t)(NT / 64) * H_DIM * 4);
    float*    partial2= (float*)alloc((size_t)64 * H_DIM * 4);
    float*    pooled  = (float*)alloc((size_t)B * H_DIM * 4);
    if (off > ws_size) return;   // workspace too small: fail visibly

    const int* esrc = eidx;
    const int* edst = eidx + E;

    dim3 blk(256);
    int gNT = (NT + 255) / 256;
    int gE  = (E + 255) / 256;
    int nb  = gNT;               // 512 scan blocks

    hipMemsetAsync(cnt, 0, (size_t)NT * 4, stream);

    k_gather_x0<<<gNT, blk, 0, stream>>>(sst, mask, x0, NT, Nn, F);
    k_count<<<gE, blk, 0, stream>>>(edst, cnt, E);
    k_dis<<<gNT, blk, 0, stream>>>(cnt, dis, NT);
    k_scan_block<<<nb, blk, 0, stream>>>(cnt, bsum, NT);
    k_scan_top<<<1, 512, 0, stream>>>(bsum, bpre, nb);
    k_scan_scatter<<<nb, blk, 0, stream>>>(cnt, bpre, startp, cursor, NT);
    k_fill<<<gE, blk, 0, stream>>>(esrc, edst, dis, cursor, csrc, cnorm, E);
    k_prepW<<<(DEPTH * H_DIM * H_DIM + 255) / 256, blk, 0, stream>>>(Ws, Wt, DEPTH * H_DIM * H_DIM);

    // layer 1: scalar -> H (fp16 residual stream)
    k_agg0<<<gNT, blk, 0, stream>>>(x0, startp, cnt, csrc, cnorm, dis, y0, NT);
    k_expand<<<(NT * 64 + 255) / 256, blk, 0, stream>>>(x0, y0, W1, b1, xh, NT);

    // layers 2..9: z = xh@W (fp16), then aggregate+bias+leaky+residual into xh
    for (int l = 0; l < DEPTH; l++) {
        k_gemm<<<NT / 128, 512, 0, stream>>>(xh, Wt + (size_t)l * H_DIM * H_DIM, zbuf);
        k_aggres<<<NT / 8, blk, 0, stream>>>(zbuf, startp, cnt, csrc, cnorm, dis,
                                             bs + (size_t)l * H_DIM, xh, NT);
    }

    // pool + head: 2048 -> 32 -> 2
    int pblocks = NT / 64;                 // 2048
    int chunksPerBatch = 16;
    int rowsPerChunk = (pblocks / B) / chunksPerBatch;   // 64
    k_pool1<<<pblocks, blk, 0, stream>>>(xh, partial);
    k_pool2<<<B * chunksPerBatch, blk, 0, stream>>>(partial, partial2, rowsPerChunk);
    k_pool3<<<B, blk, 0, stream>>>(partial2, pooled, chunksPerBatch, 1.0f / (float)Nn);
    k_head<<<B, blk, 0, stream>>>(pooled, Wh, bh, (float*)d_out);
}

// Round 8
// 1015.609 us; speedup vs baseline: 1.2727x; 1.2727x over previous
//
#include <hip/hip_runtime.h>

typedef unsigned short ushort_t;
typedef _Float16 f16x8 __attribute__((ext_vector_type(8)));
typedef float f32x4 __attribute__((ext_vector_type(4)));
typedef float f32x2 __attribute__((ext_vector_type(2)));

#define H_DIM 256
#define OUT_DIM 256

__device__ inline float lrelu(float v) { return v > 0.f ? v : 0.01f * v; }

__device__ inline unsigned short f2h(float f) {
    _Float16 h = (_Float16)f;
    unsigned short u;
    __builtin_memcpy(&u, &h, 2);
    return u;
}

__device__ inline float h2f(unsigned short u) {
    _Float16 h;
    __builtin_memcpy(&h, &u, 2);
    return (float)h;
}

// ---------- prep kernels ----------

__global__ void k_gather_x0(const float* __restrict__ sst, const int* __restrict__ mask,
                            float* __restrict__ x0, int NT, int Nn, int F) {
    int v = blockIdx.x * 256 + threadIdx.x;
    if (v < NT) {
        int b = v / Nn;
        int i = v - b * Nn;
        x0[v] = sst[(size_t)b * F + mask[i]];
    }
}

__global__ void k_count(const int* __restrict__ dst, int* __restrict__ cnt, int E) {
    int e = blockIdx.x * 256 + threadIdx.x;
    if (e < E) atomicAdd(&cnt[dst[e]], 1);
}

__global__ void k_dis(const int* __restrict__ cnt, float* __restrict__ dis, int NT) {
    int v = blockIdx.x * 256 + threadIdx.x;
    if (v < NT) dis[v] = rsqrtf((float)cnt[v] + 1.0f);
}

__global__ void k_scan_block(const int* __restrict__ cnt, int* __restrict__ bsum, int NT) {
    __shared__ int s[256];
    int i = blockIdx.x * 256 + threadIdx.x;
    s[threadIdx.x] = (i < NT) ? cnt[i] : 0;
    __syncthreads();
    for (int o = 128; o > 0; o >>= 1) {
        if (threadIdx.x < o) s[threadIdx.x] += s[threadIdx.x + o];
        __syncthreads();
    }
    if (threadIdx.x == 0) bsum[blockIdx.x] = s[0];
}

__global__ void k_scan_top(const int* __restrict__ bsum, int* __restrict__ bpre, int nb) {
    __shared__ int s[512];
    int t = threadIdx.x;
    int v = (t < nb) ? bsum[t] : 0;
    s[t] = v;
    __syncthreads();
    for (int o = 1; o < nb; o <<= 1) {
        int add = (t >= o) ? s[t - o] : 0;
        __syncthreads();
        s[t] += add;
        __syncthreads();
    }
    if (t < nb) bpre[t] = s[t] - v;   // exclusive
}

__global__ void k_scan_scatter(const int* __restrict__ cnt, const int* __restrict__ bpre,
                               int* __restrict__ startp, int* __restrict__ cursor, int NT) {
    __shared__ int s[256];
    int t = threadIdx.x;
    int i = blockIdx.x * 256 + t;
    int v = (i < NT) ? cnt[i] : 0;
    s[t] = v;
    __syncthreads();
    for (int o = 1; o < 256; o <<= 1) {
        int add = (t >= o) ? s[t - o] : 0;
        __syncthreads();
        s[t] += add;
        __syncthreads();
    }
    int excl = s[t] - v + bpre[blockIdx.x];
    if (i < NT) { startp[i] = excl; cursor[i] = excl; }
}

__global__ void k_fill(const int* __restrict__ src, const int* __restrict__ dst,
                       const float* __restrict__ dis, int* __restrict__ cursor,
                       int* __restrict__ csrc, float* __restrict__ cnorm, int E) {
    int e = blockIdx.x * 256 + threadIdx.x;
    if (e < E) {
        int s = src[e], d = dst[e];
        int p = atomicAdd(&cursor[d], 1);
        csrc[p] = s;
        cnorm[p] = dis[s] * dis[d];
    }
}

__global__ void k_prepW(const float* __restrict__ Ws, ushort_t* __restrict__ Wt, int total) {
    int idx = blockIdx.x * 256 + threadIdx.x;
    if (idx < total) {
        int l = idx >> 16;          // layer
        int rem = idx & 65535;
        int k = rem >> 8;           // input dim
        int n = rem & 255;          // output dim
        Wt[(l << 16) + (n << 8) + k] = f2h(Ws[idx]);
    }
}

// ---------- layer 1 (scalar input) ----------

__global__ void k_agg0(const float* __restrict__ x0, const int* __restrict__ startp,
                       const int* __restrict__ cnt, const int* __restrict__ csrc,
                       const float* __restrict__ cnorm, const float* __restrict__ dis,
                       float* __restrict__ y0, int NT) {
    int v = blockIdx.x * 256 + threadIdx.x;
    if (v >= NT) return;
    float d = dis[v];
    float acc = d * d * x0[v];
    int s = startp[v], e = s + cnt[v];
    for (int i = s; i < e; i++) acc += cnorm[i] * x0[csrc[i]];
    y0[v] = acc;
}

__global__ void k_expand(const float* __restrict__ x0, const float* __restrict__ y0,
                         const float* __restrict__ W1, const float* __restrict__ b1,
                         ushort_t* __restrict__ xh, int NT) {
    int idx = blockIdx.x * 256 + threadIdx.x;      // one float4-worth each, NT*64 total
    int v = idx >> 6;
    int q = idx & 63;
    if (v >= NT) return;
    float xv = x0[v], yv = y0[v];
    float4 w = ((const float4*)W1)[q];
    float4 b = ((const float4*)b1)[q];
    ushort4 o;
    o.x = f2h(xv + lrelu(yv * w.x + b.x));
    o.y = f2h(xv + lrelu(yv * w.y + b.y));
    o.z = f2h(xv + lrelu(yv * w.z + b.z));
    o.w = f2h(xv + lrelu(yv * w.w + b.w));
    ((ushort4*)xh)[(size_t)v * 64 + q] = o;
}

// ---------- GEMM: z = xh @ W (fp16 MFMA, f32 acc, fp8 e4m3 out) ----------
// xh: [NT][256] fp16, Wt: [n][k] fp16, z: [NT][256] fp8 bytes.
// Block: 512 thr = 8 waves (2 M x 4 N), tile BM=128 BN=256 BK=64.
// Epilogue: per-wave LDS repack (aliases Bs) -> coalesced dwordx4 z-stores.

__global__ __launch_bounds__(512, 4) void k_gemm(const ushort_t* __restrict__ xh,
                                                 const ushort_t* __restrict__ Wt,
                                                 unsigned char* __restrict__ z) {
    __shared__ __align__(16) ushort_t As[128][72];
    __shared__ __align__(16) ushort_t Bs[256][72];
    int tid = threadIdx.x;
    int wave = tid >> 6, lane = tid & 63;
    int wm = wave >> 2, wn = wave & 3;           // 2 x 4 wave grid, each 64x64
    size_t rowbase = (size_t)blockIdx.x * 128;

    f32x4 acc[4][4];
    for (int mi = 0; mi < 4; mi++)
        for (int ni = 0; ni < 4; ni++)
            acc[mi][ni] = (f32x4){0.f, 0.f, 0.f, 0.f};

    for (int kk = 0; kk < H_DIM; kk += 64) {
        // stage A: 128 rows x 64 fp16 (16 KB) -> 1024 16B chunks, 2 passes
        for (int p = 0; p < 2; p++) {
            int idx = p * 512 + tid;
            int r = idx >> 3, c8 = idx & 7;
            *(uint4*)&As[r][c8 * 8] = *(const uint4*)(xh + (rowbase + r) * H_DIM + kk + c8 * 8);
        }
        // stage B: 256 rows x 64 fp16 (32 KB) -> 2048 16B chunks, 4 passes
        for (int p = 0; p < 4; p++) {
            int idx = p * 512 + tid;
            int r = idx >> 3, c8 = idx & 7;
            *(uint4*)&Bs[r][c8 * 8] = *(const uint4*)(Wt + (size_t)r * H_DIM + kk + c8 * 8);
        }
        __syncthreads();
        int rl = lane & 15;
        for (int kc = 0; kc < 2; kc++) {
            int kb = kc * 32 + ((lane >> 4) << 3);
            f16x8 af[4], bfr[4];
            for (int mi = 0; mi < 4; mi++)
                af[mi] = *(const f16x8*)&As[wm * 64 + mi * 16 + rl][kb];
            for (int ni = 0; ni < 4; ni++)
                bfr[ni] = *(const f16x8*)&Bs[wn * 64 + ni * 16 + rl][kb];
            for (int mi = 0; mi < 4; mi++)
                for (int ni = 0; ni < 4; ni++)
                    acc[mi][ni] = __builtin_amdgcn_mfma_f32_16x16x32_f16(
                        af[mi], bfr[ni], acc[mi][ni], 0, 0, 0);
        }
        __syncthreads();   // also protects Bs for the epilogue repack
    }

    // epilogue: acc -> fp8 -> per-wave LDS slice [64 rows][64 cols] -> coalesced stores
    int rl = lane & 15, rh = lane >> 4;
    char* slice = (char*)&Bs[0][0] + wave * 4096;
    for (int mi = 0; mi < 4; mi++) {
        for (int ni = 0; ni < 4; ni++) {
            #pragma unroll
            for (int r = 0; r < 4; r++) {
                float vv = acc[mi][ni][r];
                int pk = __builtin_amdgcn_cvt_pk_fp8_f32(vv, vv, 0, false);
                slice[(mi * 16 + rh * 4 + r) * 64 + ni * 16 + rl] = (char)(pk & 0xFF);
            }
        }
    }
    __syncthreads();
    for (int p = 0; p < 4; p++) {
        uint4 val = *(const uint4*)(slice + p * 1024 + lane * 16);
        int lrow = p * 16 + (lane >> 2);
        int lcolb = (lane & 3) * 16;
        *(uint4*)(z + (rowbase + wm * 64 + lrow) * 256 + wn * 64 + lcolb) = val;
    }
}

// ---------- aggregate + bias + leaky + residual (in-place fp16 xh update) ----------
// One 64-lane wave per node; fp8 z rows (256B, 1 dword/lane), unroll-4 gather.

__global__ void k_aggres(const unsigned char* __restrict__ z, const int* __restrict__ startp,
                         const int* __restrict__ cnt, const int* __restrict__ csrc,
                         const float* __restrict__ cnorm, const float* __restrict__ dis,
                         const float* __restrict__ bias, ushort_t* __restrict__ xh, int NT) {
    int gid = blockIdx.x * blockDim.x + threadIdx.x;
    int v = gid >> 6;
    int lane = threadIdx.x & 63;
    if (v >= NT) return;

    // hoisted independent loads (in flight during gather)
    float d = dis[v];
    int s = startp[v], e = s + cnt[v];
    unsigned int a = *(const unsigned int*)(z + (size_t)v * 256 + lane * 4);
    ushort4 xr = *(const ushort4*)(xh + (size_t)v * H_DIM + lane * 4);
    float4 bv = *(const float4*)(bias + lane * 4);

    float sn = d * d;
    f32x2 a01 = __builtin_amdgcn_cvt_pk_f32_fp8(a, false);
    f32x2 a23 = __builtin_amdgcn_cvt_pk_f32_fp8(a, true);
    float acc0 = sn * a01[0], acc1 = sn * a01[1];
    float acc2 = sn * a23[0], acc3 = sn * a23[1];

    int i = s;
    for (; i + 4 <= e; i += 4) {
        int i0 = csrc[i], i1 = csrc[i + 1], i2 = csrc[i + 2], i3 = csrc[i + 3];
        float w0 = cnorm[i], w1 = cnorm[i + 1], w2 = cnorm[i + 2], w3 = cnorm[i + 3];
        unsigned int b0 = *(const unsigned int*)(z + (size_t)i0 * 256 + lane * 4);
        unsigned int b1 = *(const unsigned int*)(z + (size_t)i1 * 256 + lane * 4);
        unsigned int b2 = *(const unsigned int*)(z + (size_t)i2 * 256 + lane * 4);
        unsigned int b3 = *(const unsigned int*)(z + (size_t)i3 * 256 + lane * 4);
        f32x2 p0 = __builtin_amdgcn_cvt_pk_f32_fp8(b0, false);
        f32x2 q0 = __builtin_amdgcn_cvt_pk_f32_fp8(b0, true);
        f32x2 p1 = __builtin_amdgcn_cvt_pk_f32_fp8(b1, false);
        f32x2 q1 = __builtin_amdgcn_cvt_pk_f32_fp8(b1, true);
        f32x2 p2 = __builtin_amdgcn_cvt_pk_f32_fp8(b2, false);
        f32x2 q2 = __builtin_amdgcn_cvt_pk_f32_fp8(b2, true);
        f32x2 p3 = __builtin_amdgcn_cvt_pk_f32_fp8(b3, false);
        f32x2 q3 = __builtin_amdgcn_cvt_pk_f32_fp8(b3, true);
        acc0 += w0 * p0[0] + w1 * p1[0] + w2 * p2[0] + w3 * p3[0];
        acc1 += w0 * p0[1] + w1 * p1[1] + w2 * p2[1] + w3 * p3[1];
        acc2 += w0 * q0[0] + w1 * q1[0] + w2 * q2[0] + w3 * q3[0];
        acc3 += w0 * q0[1] + w1 * q1[1] + w2 * q2[1] + w3 * q3[1];
    }
    for (; i < e; i++) {
        int sv = csrc[i];
        float nw = cnorm[i];
        unsigned int b = *(const unsigned int*)(z + (size_t)sv * 256 + lane * 4);
        f32x2 p = __builtin_amdgcn_cvt_pk_f32_fp8(b, false);
        f32x2 q = __builtin_amdgcn_cvt_pk_f32_fp8(b, true);
        acc0 += nw * p[0]; acc1 += nw * p[1];
        acc2 += nw * q[0]; acc3 += nw * q[1];
    }

    ushort4 o;
    o.x = f2h(h2f(xr.x) + lrelu(acc0 + bv.x));
    o.y = f2h(h2f(xr.y) + lrelu(acc1 + bv.y));
    o.z = f2h(h2f(xr.z) + lrelu(acc2 + bv.z));
    o.w = f2h(h2f(xr.w) + lrelu(acc3 + bv.w));
    *(ushort4*)(xh + (size_t)v * H_DIM + lane * 4) = o;
}

// ---------- pooling (3-stage tree) + head ----------

__global__ void k_pool1(const ushort_t* __restrict__ xh, float* __restrict__ partial) {
    __shared__ float s[4][256];
    int t = threadIdx.x;
    int w = t >> 6, lane = t & 63;
    size_t nodebase = (size_t)blockIdx.x * 64;
    float4 acc = make_float4(0.f, 0.f, 0.f, 0.f);
    for (int i = 0; i < 16; i++) {
        size_t node = nodebase + i * 4 + w;
        ushort4 v = *(const ushort4*)(xh + node * H_DIM + lane * 4);
        acc.x += h2f(v.x); acc.y += h2f(v.y); acc.z += h2f(v.z); acc.w += h2f(v.w);
    }
    *(float4*)&s[w][lane * 4] = acc;
    __syncthreads();
    float sum = s[0][t] + s[1][t] + s[2][t] + s[3][t];
    partial[(size_t)blockIdx.x * H_DIM + t] = sum;
}

__global__ void k_pool2(const float* __restrict__ partial, float* __restrict__ partial2,
                        int rowsPerChunk) {
    int blk = blockIdx.x, t = threadIdx.x;
    size_t rowbase = (size_t)blk * rowsPerChunk;
    float s = 0.f;
    for (int j = 0; j < rowsPerChunk; j++)
        s += partial[(rowbase + j) * H_DIM + t];
    partial2[(size_t)blk * H_DIM + t] = s;
}

__global__ void k_pool3(const float* __restrict__ partial2, float* __restrict__ pooled,
                        int chunksPerBatch, float inv) {
    int b = blockIdx.x, t = threadIdx.x;
    float s = 0.f;
    for (int j = 0; j < chunksPerBatch; j++)
        s += partial2[((size_t)b * chunksPerBatch + j) * H_DIM + t];
    pooled[b * H_DIM + t] = s * inv;
}

__global__ void k_head(const float* __restrict__ pooled, const float* __restrict__ Wh,
                       const float* __restrict__ bh, float* __restrict__ out) {
    int b = blockIdx.x, o = threadIdx.x;
    float acc = bh[o];
    for (int h = 0; h < H_DIM; h++) acc += pooled[b * H_DIM + h] * Wh[h * OUT_DIM + o];
    out[b * OUT_DIM + o] = acc;
}

// ---------- host ----------

extern "C" void kernel_launch(void* const* d_in, const int* in_sizes, int n_in,
                              void* d_out, int out_size, void* d_ws, size_t ws_size,
                              hipStream_t stream) {
    const float* sst  = (const float*)d_in[0];
    const int*   mask = (const int*)d_in[1];
    const int*   eidx = (const int*)d_in[2];
    const float* W1   = (const float*)d_in[3];
    const float* b1   = (const float*)d_in[4];
    const float* Ws   = (const float*)d_in[5];
    const float* bs   = (const float*)d_in[6];
    const float* Wh   = (const float*)d_in[7];
    const float* bh   = (const float*)d_in[8];

    const int B  = out_size / OUT_DIM;               // 2
    const int Nn = in_sizes[1];                      // 65536
    const int E  = in_sizes[2] / 2;                  // 1048576
    const int F  = in_sizes[0] / B;                  // 686364
    const int DEPTH = in_sizes[5] / (H_DIM * H_DIM); // 8
    const int NT = B * Nn;                           // 131072

    // workspace carve-up (256B aligned) — total ~145 MB
    size_t off = 0;
    char* base = (char*)d_ws;
    auto alloc = [&](size_t bytes) -> void* {
        void* p = base + off;
        off += (bytes + 255) & ~(size_t)255;
        return p;
    };
    ushort_t*      xh      = (ushort_t*)alloc((size_t)NT * H_DIM * 2);  // 67.1 MB fp16 residual
    unsigned char* zbuf    = (unsigned char*)alloc((size_t)NT * 256);   // 33.5 MB fp8
    float*    x0      = (float*)alloc((size_t)NT * 4);
    float*    y0      = (float*)alloc((size_t)NT * 4);
    int*      cnt     = (int*)alloc((size_t)NT * 4);
    int*      startp  = (int*)alloc((size_t)NT * 4);
    int*      cursor  = (int*)alloc((size_t)NT * 4);
    float*    dis     = (float*)alloc((size_t)NT * 4);
    int*      bsum    = (int*)alloc(4096);
    int*      bpre    = (int*)alloc(4096);
    int*      csrc    = (int*)alloc((size_t)E * 4);
    float*    cnorm   = (float*)alloc((size_t)E * 4);
    ushort_t* Wt      = (ushort_t*)alloc((size_t)DEPTH * H_DIM * H_DIM * 2);  // fp16
    float*    partial = (float*)alloc((size_t)(NT / 64) * H_DIM * 4);
    float*    partial2= (float*)alloc((size_t)64 * H_DIM * 4);
    float*    pooled  = (float*)alloc((size_t)B * H_DIM * 4);
    if (off > ws_size) return;   // workspace too small: fail visibly

    const int* esrc = eidx;
    const int* edst = eidx + E;

    dim3 blk(256);
    int gNT = (NT + 255) / 256;
    int gE  = (E + 255) / 256;
    int nb  = gNT;               // 512 scan blocks

    hipMemsetAsync(cnt, 0, (size_t)NT * 4, stream);

    k_gather_x0<<<gNT, blk, 0, stream>>>(sst, mask, x0, NT, Nn, F);
    k_count<<<gE, blk, 0, stream>>>(edst, cnt, E);
    k_dis<<<gNT, blk, 0, stream>>>(cnt, dis, NT);
    k_scan_block<<<nb, blk, 0, stream>>>(cnt, bsum, NT);
    k_scan_top<<<1, 512, 0, stream>>>(bsum, bpre, nb);
    k_scan_scatter<<<nb, blk, 0, stream>>>(cnt, bpre, startp, cursor, NT);
    k_fill<<<gE, blk, 0, stream>>>(esrc, edst, dis, cursor, csrc, cnorm, E);
    k_prepW<<<(DEPTH * H_DIM * H_DIM + 255) / 256, blk, 0, stream>>>(Ws, Wt, DEPTH * H_DIM * H_DIM);

    // layer 1: scalar -> H (fp16 residual stream)
    k_agg0<<<gNT, blk, 0, stream>>>(x0, startp, cnt, csrc, cnorm, dis, y0, NT);
    k_expand<<<(NT * 64 + 255) / 256, blk, 0, stream>>>(x0, y0, W1, b1, xh, NT);

    // layers 2..9: z = xh@W (fp8 out), then aggregate+bias+leaky+residual into xh
    for (int l = 0; l < DEPTH; l++) {
        k_gemm<<<NT / 128, 512, 0, stream>>>(xh, Wt + (size_t)l * H_DIM * H_DIM, zbuf);
        k_aggres<<<NT / 4, blk, 0, stream>>>(zbuf, startp, cnt, csrc, cnorm, dis,
                                             bs + (size_t)l * H_DIM, xh, NT);
    }

    // pool + head: 2048 -> 32 -> 2
    int pblocks = NT / 64;                 // 2048
    int chunksPerBatch = 16;
    int rowsPerChunk = (pblocks / B) / chunksPerBatch;   // 64
    k_pool1<<<pblocks, blk, 0, stream>>>(xh, partial);
    k_pool2<<<B * chunksPerBatch, blk, 0, stream>>>(partial, partial2, rowsPerChunk);
    k_pool3<<<B, blk, 0, stream>>>(partial2, pooled, chunksPerBatch, 1.0f / (float)Nn);
    k_head<<<B, blk, 0, stream>>>(pooled, Wh, bh, (float*)d_out);
}

// Round 9
// 975.313 us; speedup vs baseline: 1.3253x; 1.0413x over previous
//
#include <hip/hip_runtime.h>

typedef unsigned short ushort_t;
typedef _Float16 f16x8 __attribute__((ext_vector_type(8)));
typedef float f32x4 __attribute__((ext_vector_type(4)));
typedef float f32x2 __attribute__((ext_vector_type(2)));

#define H_DIM 256
#define OUT_DIM 256

__device__ inline float lrelu(float v) { return v > 0.f ? v : 0.01f * v; }

__device__ inline unsigned short f2h(float f) {
    _Float16 h = (_Float16)f;
    unsigned short u;
    __builtin_memcpy(&u, &h, 2);
    return u;
}

__device__ inline float h2f(unsigned short u) {
    _Float16 h;
    __builtin_memcpy(&h, &u, 2);
    return (float)h;
}

// ---------- prep kernels ----------

__global__ void k_gather_x0(const float* __restrict__ sst, const int* __restrict__ mask,
                            float* __restrict__ x0, int NT, int Nn, int F) {
    int v = blockIdx.x * 256 + threadIdx.x;
    if (v < NT) {
        int b = v / Nn;
        int i = v - b * Nn;
        x0[v] = sst[(size_t)b * F + mask[i]];
    }
}

__global__ void k_count(const int* __restrict__ dst, int* __restrict__ cnt, int E) {
    int e = blockIdx.x * 256 + threadIdx.x;
    if (e < E) atomicAdd(&cnt[dst[e]], 1);
}

__global__ void k_dis(const int* __restrict__ cnt, float* __restrict__ dis, int NT) {
    int v = blockIdx.x * 256 + threadIdx.x;
    if (v < NT) dis[v] = rsqrtf((float)cnt[v] + 1.0f);
}

__global__ void k_scan_block(const int* __restrict__ cnt, int* __restrict__ bsum, int NT) {
    __shared__ int s[256];
    int i = blockIdx.x * 256 + threadIdx.x;
    s[threadIdx.x] = (i < NT) ? cnt[i] : 0;
    __syncthreads();
    for (int o = 128; o > 0; o >>= 1) {
        if (threadIdx.x < o) s[threadIdx.x] += s[threadIdx.x + o];
        __syncthreads();
    }
    if (threadIdx.x == 0) bsum[blockIdx.x] = s[0];
}

__global__ void k_scan_top(const int* __restrict__ bsum, int* __restrict__ bpre, int nb) {
    __shared__ int s[512];
    int t = threadIdx.x;
    int v = (t < nb) ? bsum[t] : 0;
    s[t] = v;
    __syncthreads();
    for (int o = 1; o < nb; o <<= 1) {
        int add = (t >= o) ? s[t - o] : 0;
        __syncthreads();
        s[t] += add;
        __syncthreads();
    }
    if (t < nb) bpre[t] = s[t] - v;   // exclusive
}

__global__ void k_scan_scatter(const int* __restrict__ cnt, const int* __restrict__ bpre,
                               int* __restrict__ startp, int* __restrict__ cursor, int NT) {
    __shared__ int s[256];
    int t = threadIdx.x;
    int i = blockIdx.x * 256 + t;
    int v = (i < NT) ? cnt[i] : 0;
    s[t] = v;
    __syncthreads();
    for (int o = 1; o < 256; o <<= 1) {
        int add = (t >= o) ? s[t - o] : 0;
        __syncthreads();
        s[t] += add;
        __syncthreads();
    }
    int excl = s[t] - v + bpre[blockIdx.x];
    if (i < NT) { startp[i] = excl; cursor[i] = excl; }
}

__global__ void k_fill(const int* __restrict__ src, const int* __restrict__ dst,
                       const float* __restrict__ dis, int* __restrict__ cursor,
                       int* __restrict__ csrc, float* __restrict__ cnorm, int E) {
    int e = blockIdx.x * 256 + threadIdx.x;
    if (e < E) {
        int s = src[e], d = dst[e];
        int p = atomicAdd(&cursor[d], 1);
        csrc[p] = s;
        cnorm[p] = dis[s] * dis[d];
    }
}

__global__ void k_prepW(const float* __restrict__ Ws, ushort_t* __restrict__ Wt, int total) {
    int idx = blockIdx.x * 256 + threadIdx.x;
    if (idx < total) {
        int l = idx >> 16;          // layer
        int rem = idx & 65535;
        int k = rem >> 8;           // input dim
        int n = rem & 255;          // output dim
        Wt[(l << 16) + (n << 8) + k] = f2h(Ws[idx]);
    }
}

// ---------- layer 1 (scalar input) ----------

__global__ void k_agg0(const float* __restrict__ x0, const int* __restrict__ startp,
                       const int* __restrict__ cnt, const int* __restrict__ csrc,
                       const float* __restrict__ cnorm, const float* __restrict__ dis,
                       float* __restrict__ y0, int NT) {
    int v = blockIdx.x * 256 + threadIdx.x;
    if (v >= NT) return;
    float d = dis[v];
    float acc = d * d * x0[v];
    int s = startp[v], e = s + cnt[v];
    for (int i = s; i < e; i++) acc += cnorm[i] * x0[csrc[i]];
    y0[v] = acc;
}

__global__ void k_expand(const float* __restrict__ x0, const float* __restrict__ y0,
                         const float* __restrict__ W1, const float* __restrict__ b1,
                         ushort_t* __restrict__ xh, int NT) {
    int idx = blockIdx.x * 256 + threadIdx.x;      // one float4-worth each, NT*64 total
    int v = idx >> 6;
    int q = idx & 63;
    if (v >= NT) return;
    float xv = x0[v], yv = y0[v];
    float4 w = ((const float4*)W1)[q];
    float4 b = ((const float4*)b1)[q];
    ushort4 o;
    o.x = f2h(xv + lrelu(yv * w.x + b.x));
    o.y = f2h(xv + lrelu(yv * w.y + b.y));
    o.z = f2h(xv + lrelu(yv * w.z + b.z));
    o.w = f2h(xv + lrelu(yv * w.w + b.w));
    ((ushort4*)xh)[(size_t)v * 64 + q] = o;
}

// ---------- GEMM: z = xh @ W (fp16 MFMA, f32 acc, fp8 e4m3 out) ----------
// W held in REGISTERS (loaded once/block from L2); A staged once per 64-row tile
// for the FULL K=256 with XOR-swizzled LDS ([row][col^((row&7)<<4)]).
// Block: 256 thr = 4 waves, wave w owns cols [w*64, w*64+64) of all 64 rows.
// Grid-stride over NT/64 tiles. One barrier pair per tile.

__global__ __launch_bounds__(256) void k_gemm(const ushort_t* __restrict__ xh,
                                              const ushort_t* __restrict__ Wt,
                                              unsigned char* __restrict__ z, int NT) {
    __shared__ __align__(16) char AsRaw[64 * 512];    // 32 KB: 64 rows x 512B (swizzled)
    __shared__ __align__(16) char Rep[4][4096];       // 16 KB: per-wave fp8 repack
    int tid = threadIdx.x;
    int wave = tid >> 6, lane = tid & 63;
    int rl = lane & 15, hi = lane >> 4;               // hi in 0..3

    // ---- W fragments into registers: wave owns n-cols [wave*64, +64) ----
    // frag (ni,c): lane holds Wt[wave*64+ni*16+rl][c*32 + hi*8 + 0..7]
    f16x8 bf[4][8];
    #pragma unroll
    for (int ni = 0; ni < 4; ni++)
        #pragma unroll
        for (int c = 0; c < 8; c++)
            bf[ni][c] = *(const f16x8*)(Wt + (size_t)(wave * 64 + ni * 16 + rl) * 256
                                        + c * 32 + hi * 8);

    int ntiles = NT / 64;
    for (int t = blockIdx.x; t < ntiles; t += gridDim.x) {
        size_t rowbase = (size_t)t * 64;

        // ---- stage A tile: 64 rows x 256 fp16, swizzled write ----
        #pragma unroll
        for (int p = 0; p < 8; p++) {
            int idx = p * 256 + tid;          // 2048 chunks of 16B
            int row = idx >> 5;
            int colb = (idx & 31) * 16;
            uint4 vsrc = *(const uint4*)(xh + (rowbase + row) * H_DIM + (idx & 31) * 8);
            *(uint4*)(AsRaw + row * 512 + (colb ^ ((row & 7) << 4))) = vsrc;
        }
        __syncthreads();

        // ---- MFMA: 8 k-chunks x (4 mi x 4 ni) ----
        f32x4 acc[4][4];
        #pragma unroll
        for (int mi = 0; mi < 4; mi++)
            #pragma unroll
            for (int ni = 0; ni < 4; ni++)
                acc[mi][ni] = (f32x4){0.f, 0.f, 0.f, 0.f};

        #pragma unroll
        for (int c = 0; c < 8; c++) {
            f16x8 af[4];
            #pragma unroll
            for (int mi = 0; mi < 4; mi++) {
                int row = mi * 16 + rl;
                int colb = c * 64 + hi * 16;
                af[mi] = *(const f16x8*)(AsRaw + row * 512 + (colb ^ ((row & 7) << 4)));
            }
            #pragma unroll
            for (int mi = 0; mi < 4; mi++)
                #pragma unroll
                for (int ni = 0; ni < 4; ni++)
                    acc[mi][ni] = __builtin_amdgcn_mfma_f32_16x16x32_f16(
                        af[mi], bf[ni][c], acc[mi][ni], 0, 0, 0);
        }
        __syncthreads();   // As free for next tile's stage

        // ---- epilogue: fp8 pack -> per-wave LDS slice -> coalesced stores ----
        char* slice = &Rep[wave][0];
        #pragma unroll
        for (int mi = 0; mi < 4; mi++)
            #pragma unroll
            for (int ni = 0; ni < 4; ni++)
                #pragma unroll
                for (int r = 0; r < 4; r++) {
                    float vv = acc[mi][ni][r];
                    int pk = __builtin_amdgcn_cvt_pk_fp8_f32(vv, vv, 0, false);
                    slice[(mi * 16 + hi * 4 + r) * 64 + ni * 16 + rl] = (char)(pk & 0xFF);
                }
        #pragma unroll
        for (int p = 0; p < 4; p++) {
            uint4 val = *(const uint4*)(slice + p * 1024 + lane * 16);
            int lrow = p * 16 + (lane >> 2);
            int lcolb = (lane & 3) * 16;
            *(uint4*)(z + (rowbase + lrow) * 256 + wave * 64 + lcolb) = val;
        }
    }
}

// ---------- aggregate + bias + leaky + residual (in-place fp16 xh update) ----------
// One 64-lane wave per node; fp8 z rows (256B, 1 dword/lane), unroll-4 gather.

__global__ void k_aggres(const unsigned char* __restrict__ z, const int* __restrict__ startp,
                         const int* __restrict__ cnt, const int* __restrict__ csrc,
                         const float* __restrict__ cnorm, const float* __restrict__ dis,
                         const float* __restrict__ bias, ushort_t* __restrict__ xh, int NT) {
    int gid = blockIdx.x * blockDim.x + threadIdx.x;
    int v = gid >> 6;
    int lane = threadIdx.x & 63;
    if (v >= NT) return;

    // hoisted independent loads (in flight during gather)
    float d = dis[v];
    int s = startp[v], e = s + cnt[v];
    unsigned int a = *(const unsigned int*)(z + (size_t)v * 256 + lane * 4);
    ushort4 xr = *(const ushort4*)(xh + (size_t)v * H_DIM + lane * 4);
    float4 bv = *(const float4*)(bias + lane * 4);

    float sn = d * d;
    f32x2 a01 = __builtin_amdgcn_cvt_pk_f32_fp8(a, false);
    f32x2 a23 = __builtin_amdgcn_cvt_pk_f32_fp8(a, true);
    float acc0 = sn * a01[0], acc1 = sn * a01[1];
    float acc2 = sn * a23[0], acc3 = sn * a23[1];

    int i = s;
    for (; i + 4 <= e; i += 4) {
        int i0 = csrc[i], i1 = csrc[i + 1], i2 = csrc[i + 2], i3 = csrc[i + 3];
        float w0 = cnorm[i], w1 = cnorm[i + 1], w2 = cnorm[i + 2], w3 = cnorm[i + 3];
        unsigned int b0 = *(const unsigned int*)(z + (size_t)i0 * 256 + lane * 4);
        unsigned int b1 = *(const unsigned int*)(z + (size_t)i1 * 256 + lane * 4);
        unsigned int b2 = *(const unsigned int*)(z + (size_t)i2 * 256 + lane * 4);
        unsigned int b3 = *(const unsigned int*)(z + (size_t)i3 * 256 + lane * 4);
        f32x2 p0 = __builtin_amdgcn_cvt_pk_f32_fp8(b0, false);
        f32x2 q0 = __builtin_amdgcn_cvt_pk_f32_fp8(b0, true);
        f32x2 p1 = __builtin_amdgcn_cvt_pk_f32_fp8(b1, false);
        f32x2 q1 = __builtin_amdgcn_cvt_pk_f32_fp8(b1, true);
        f32x2 p2 = __builtin_amdgcn_cvt_pk_f32_fp8(b2, false);
        f32x2 q2 = __builtin_amdgcn_cvt_pk_f32_fp8(b2, true);
        f32x2 p3 = __builtin_amdgcn_cvt_pk_f32_fp8(b3, false);
        f32x2 q3 = __builtin_amdgcn_cvt_pk_f32_fp8(b3, true);
        acc0 += w0 * p0[0] + w1 * p1[0] + w2 * p2[0] + w3 * p3[0];
        acc1 += w0 * p0[1] + w1 * p1[1] + w2 * p2[1] + w3 * p3[1];
        acc2 += w0 * q0[0] + w1 * q1[0] + w2 * q2[0] + w3 * q3[0];
        acc3 += w0 * q0[1] + w1 * q1[1] + w2 * q2[1] + w3 * q3[1];
    }
    for (; i < e; i++) {
        int sv = csrc[i];
        float nw = cnorm[i];
        unsigned int b = *(const unsigned int*)(z + (size_t)sv * 256 + lane * 4);
        f32x2 p = __builtin_amdgcn_cvt_pk_f32_fp8(b, false);
        f32x2 q = __builtin_amdgcn_cvt_pk_f32_fp8(b, true);
        acc0 += nw * p[0]; acc1 += nw * p[1];
        acc2 += nw * q[0]; acc3 += nw * q[1];
    }

    ushort4 o;
    o.x = f2h(h2f(xr.x) + lrelu(acc0 + bv.x));
    o.y = f2h(h2f(xr.y) + lrelu(acc1 + bv.y));
    o.z = f2h(h2f(xr.z) + lrelu(acc2 + bv.z));
    o.w = f2h(h2f(xr.w) + lrelu(acc3 + bv.w));
    *(ushort4*)(xh + (size_t)v * H_DIM + lane * 4) = o;
}

// ---------- pooling (3-stage tree) + head ----------

__global__ void k_pool1(const ushort_t* __restrict__ xh, float* __restrict__ partial) {
    __shared__ float s[4][256];
    int t = threadIdx.x;
    int w = t >> 6, lane = t & 63;
    size_t nodebase = (size_t)blockIdx.x * 64;
    float4 acc = make_float4(0.f, 0.f, 0.f, 0.f);
    for (int i = 0; i < 16; i++) {
        size_t node = nodebase + i * 4 + w;
        ushort4 v = *(const ushort4*)(xh + node * H_DIM + lane * 4);
        acc.x += h2f(v.x); acc.y += h2f(v.y); acc.z += h2f(v.z); acc.w += h2f(v.w);
    }
    *(float4*)&s[w][lane * 4] = acc;
    __syncthreads();
    float sum = s[0][t] + s[1][t] + s[2][t] + s[3][t];
    partial[(size_t)blockIdx.x * H_DIM + t] = sum;
}

__global__ void k_pool2(const float* __restrict__ partial, float* __restrict__ partial2,
                        int rowsPerChunk) {
    int blk = blockIdx.x, t = threadIdx.x;
    size_t rowbase = (size_t)blk * rowsPerChunk;
    float s = 0.f;
    for (int j = 0; j < rowsPerChunk; j++)
        s += partial[(rowbase + j) * H_DIM + t];
    partial2[(size_t)blk * H_DIM + t] = s;
}

__global__ void k_pool3(const float* __restrict__ partial2, float* __restrict__ pooled,
                        int chunksPerBatch, float inv) {
    int b = blockIdx.x, t = threadIdx.x;
    float s = 0.f;
    for (int j = 0; j < chunksPerBatch; j++)
        s += partial2[((size_t)b * chunksPerBatch + j) * H_DIM + t];
    pooled[b * H_DIM + t] = s * inv;
}

__global__ void k_head(const float* __restrict__ pooled, const float* __restrict__ Wh,
                       const float* __restrict__ bh, float* __restrict__ out) {
    int b = blockIdx.x, o = threadIdx.x;
    float acc = bh[o];
    for (int h = 0; h < H_DIM; h++) acc += pooled[b * H_DIM + h] * Wh[h * OUT_DIM + o];
    out[b * OUT_DIM + o] = acc;
}

// ---------- host ----------

extern "C" void kernel_launch(void* const* d_in, const int* in_sizes, int n_in,
                              void* d_out, int out_size, void* d_ws, size_t ws_size,
                              hipStream_t stream) {
    const float* sst  = (const float*)d_in[0];
    const int*   mask = (const int*)d_in[1];
    const int*   eidx = (const int*)d_in[2];
    const float* W1   = (const float*)d_in[3];
    const float* b1   = (const float*)d_in[4];
    const float* Ws   = (const float*)d_in[5];
    const float* bs   = (const float*)d_in[6];
    const float* Wh   = (const float*)d_in[7];
    const float* bh   = (const float*)d_in[8];

    const int B  = out_size / OUT_DIM;               // 2
    const int Nn = in_sizes[1];                      // 65536
    const int E  = in_sizes[2] / 2;                  // 1048576
    const int F  = in_sizes[0] / B;                  // 686364
    const int DEPTH = in_sizes[5] / (H_DIM * H_DIM); // 8
    const int NT = B * Nn;                           // 131072

    // workspace carve-up (256B aligned) — total ~145 MB
    size_t off = 0;
    char* base = (char*)d_ws;
    auto alloc = [&](size_t bytes) -> void* {
        void* p = base + off;
        off += (bytes + 255) & ~(size_t)255;
        return p;
    };
    ushort_t*      xh      = (ushort_t*)alloc((size_t)NT * H_DIM * 2);  // 67.1 MB fp16 residual
    unsigned char* zbuf    = (unsigned char*)alloc((size_t)NT * 256);   // 33.5 MB fp8
    float*    x0      = (float*)alloc((size_t)NT * 4);
    float*    y0      = (float*)alloc((size_t)NT * 4);
    int*      cnt     = (int*)alloc((size_t)NT * 4);
    int*      startp  = (int*)alloc((size_t)NT * 4);
    int*      cursor  = (int*)alloc((size_t)NT * 4);
    float*    dis     = (float*)alloc((size_t)NT * 4);
    int*      bsum    = (int*)alloc(4096);
    int*      bpre    = (int*)alloc(4096);
    int*      csrc    = (int*)alloc((size_t)E * 4);
    float*    cnorm   = (float*)alloc((size_t)E * 4);
    ushort_t* Wt      = (ushort_t*)alloc((size_t)DEPTH * H_DIM * H_DIM * 2);  // fp16
    float*    partial = (float*)alloc((size_t)(NT / 64) * H_DIM * 4);
    float*    partial2= (float*)alloc((size_t)64 * H_DIM * 4);
    float*    pooled  = (float*)alloc((size_t)B * H_DIM * 4);
    if (off > ws_size) return;   // workspace too small: fail visibly

    const int* esrc = eidx;
    const int* edst = eidx + E;

    dim3 blk(256);
    int gNT = (NT + 255) / 256;
    int gE  = (E + 255) / 256;
    int nb  = gNT;               // 512 scan blocks

    hipMemsetAsync(cnt, 0, (size_t)NT * 4, stream);

    k_gather_x0<<<gNT, blk, 0, stream>>>(sst, mask, x0, NT, Nn, F);
    k_count<<<gE, blk, 0, stream>>>(edst, cnt, E);
    k_dis<<<gNT, blk, 0, stream>>>(cnt, dis, NT);
    k_scan_block<<<nb, blk, 0, stream>>>(cnt, bsum, NT);
    k_scan_top<<<1, 512, 0, stream>>>(bsum, bpre, nb);
    k_scan_scatter<<<nb, blk, 0, stream>>>(cnt, bpre, startp, cursor, NT);
    k_fill<<<gE, blk, 0, stream>>>(esrc, edst, dis, cursor, csrc, cnorm, E);
    k_prepW<<<(DEPTH * H_DIM * H_DIM + 255) / 256, blk, 0, stream>>>(Ws, Wt, DEPTH * H_DIM * H_DIM);

    // layer 1: scalar -> H (fp16 residual stream)
    k_agg0<<<gNT, blk, 0, stream>>>(x0, startp, cnt, csrc, cnorm, dis, y0, NT);
    k_expand<<<(NT * 64 + 255) / 256, blk, 0, stream>>>(x0, y0, W1, b1, xh, NT);

    // layers 2..9: z = xh@W (fp8 out), then aggregate+bias+leaky+residual into xh
    for (int l = 0; l < DEPTH; l++) {
        k_gemm<<<512, blk, 0, stream>>>(xh, Wt + (size_t)l * H_DIM * H_DIM, zbuf, NT);
        k_aggres<<<NT / 4, blk, 0, stream>>>(zbuf, startp, cnt, csrc, cnorm, dis,
                                             bs + (size_t)l * H_DIM, xh, NT);
    }

    // pool + head: 2048 -> 32 -> 2
    int pblocks = NT / 64;                 // 2048
    int chunksPerBatch = 16;
    int rowsPerChunk = (pblocks / B) / chunksPerBatch;   // 64
    k_pool1<<<pblocks, blk, 0, stream>>>(xh, partial);
    k_pool2<<<B * chunksPerBatch, blk, 0, stream>>>(partial, partial2, rowsPerChunk);
    k_pool3<<<B, blk, 0, stream>>>(partial2, pooled, chunksPerBatch, 1.0f / (float)Nn);
    k_head<<<B, blk, 0, stream>>>(pooled, Wh, bh, (float*)d_out);
}